// Round 2
// baseline (51428.809 us; speedup 1.0000x reference)
//
#include <hip/hip_runtime.h>

// MANN/NTM encoder, MI355X persistent-kernel design.
// T=256 sequential steps; one cooperative kernel holds all recurrent state:
//   - mem[b] (1024x64 fp32) split across 2 WGs/batch, resident in LDS (128KB+pad)
//   - c (LSTM cell) resident in registers of the gate-GEMM waves
//   - per-step: [A: split-bf16 MFMA gates GEMM + LSTM] gbar [B: keys+softmax+read+write] gbar
// Precision: weights & recurrent activations (h, r) as bf16 hi+lo pairs; 3-term MFMA
// (Ahi*Whi + Alo*Whi + Ahi*Wlo) gives ~fp32 gates; emb kept single-bf16 (non-recurrent).

#define T_STEPS 256
#define BSZ     128
#define IDIM    512
#define CDIM    512
#define NSLOT   1024
#define MW      64
#define G4      2048   // 4*CDIM
#define ODIM    576

typedef unsigned short u16;
typedef unsigned int   u32;
typedef short  short8  __attribute__((ext_vector_type(8)));
typedef float  floatx4 __attribute__((ext_vector_type(4)));

__device__ __forceinline__ float bf2f(u16 h){ return __uint_as_float(((u32)h)<<16); }
__device__ __forceinline__ u16   f2bf(float f){ u32 u = __float_as_uint(f); return (u16)((u + 0x7fffu + ((u>>16)&1u))>>16); }
__device__ __forceinline__ float sigm(float x){ return 1.f/(1.f+__expf(-x)); }

// ---------------- prep kernels ----------------

// embs fp32 -> bf16 (33.5 MB), 4 elems/thread
__global__ void prep_embs(const float* __restrict__ e, u16* __restrict__ o){
    int i = blockIdx.x*256 + threadIdx.x;            // 4194304 threads
    float4 v = ((const float4*)e)[i];
    u32 lo = (u32)f2bf(v.x) | ((u32)f2bf(v.y)<<16);
    u32 hi = (u32)f2bf(v.z) | ((u32)f2bf(v.w)<<16);
    *(uint2*)&o[(size_t)i*4] = make_uint2(lo,hi);
}

// Pack W = [w_ih | w_hh] -> bf16 hi/lo, gate-interleaved cols (j = 4n+g), k-major-8:
//   entry (kg,j) at WT[(kg*2048 + j)*16] = [hi0..hi7 | lo0..lo7], orig row ro=(j&3)*512+(j>>2)
__global__ void prep_wt(const float* __restrict__ wih, const float* __restrict__ whh,
                        const float* __restrict__ bih, const float* __restrict__ bhh,
                        u16* __restrict__ WT, float* __restrict__ biasp){
    int idx = blockIdx.x*256 + threadIdx.x;          // 136*2048 = 278528
    if (idx >= 136*G4) return;
    int j  = idx & (G4-1);
    int kg = idx >> 11;
    int ro = (j&3)*512 + (j>>2);
    u32 ohi[4], olo[4];
    #pragma unroll
    for (int p=0;p<4;p++){
        int k0 = kg*8 + p*2;
        float v0 = (k0   < 576) ? wih[ro*576 + k0  ] : whh[ro*512 + k0   - 576];
        float v1 = (k0+1 < 576) ? wih[ro*576 + k0+1] : whh[ro*512 + k0+1 - 576];
        u16 h0b = f2bf(v0), h1b = f2bf(v1);
        u16 l0b = f2bf(v0 - bf2f(h0b)), l1b = f2bf(v1 - bf2f(h1b));
        ohi[p] = (u32)h0b | ((u32)h1b<<16);
        olo[p] = (u32)l0b | ((u32)l1b<<16);
    }
    *(uint4*)&WT[(size_t)idx*16]     = make_uint4(ohi[0],ohi[1],ohi[2],ohi[3]);
    *(uint4*)&WT[(size_t)idx*16 + 8] = make_uint4(olo[0],olo[1],olo[2],olo[3]);
    if (idx < G4) biasp[j] = bih[ro] + bhh[ro];
}

// key weights (k_r,k_w,e,a = 256 rows x 512) bf16 interleaved; key biases;
// h/r hi-lo state init; zero sync flags.
__global__ void prep_misc(const float* __restrict__ Wrk, const float* __restrict__ Wwk,
                          const float* __restrict__ We,  const float* __restrict__ Wa,
                          const float* __restrict__ brk, const float* __restrict__ bwk,
                          const float* __restrict__ be,  const float* __restrict__ ba,
                          const float* __restrict__ h0,  const float* __restrict__ r0,
                          u16* __restrict__ Wk, float* __restrict__ kb,
                          u16* __restrict__ hhi, u16* __restrict__ hlo,
                          u16* __restrict__ xrhi, u16* __restrict__ xrlo,
                          u32* __restrict__ pflags, u32* __restrict__ gsync){
    int idx = blockIdx.x*256 + threadIdx.x;          // needs 110912, grid gives 131072
    if (idx < 32768) {
        int d4 = idx >> 8, k = idx & 255;
        const float* src = (k<64)? Wrk + k*512 : (k<128)? Wwk + (k-64)*512
                         : (k<192)? We + (k-128)*512 : Wa + (k-192)*512;
        u32 a = (u32)f2bf(src[d4*4+0]) | ((u32)f2bf(src[d4*4+1])<<16);
        u32 b = (u32)f2bf(src[d4*4+2]) | ((u32)f2bf(src[d4*4+3])<<16);
        *(uint2*)&Wk[(size_t)idx*4] = make_uint2(a,b);
    } else if (idx < 33024) {
        int k = idx - 32768;
        kb[k] = (k<64)? brk[k] : (k<128)? bwk[k-64] : (k<192)? be[k-128] : ba[k-192];
    } else if (idx < 33024+65536) {
        int i = idx - 33024;
        float v = h0[i & 511];
        u16 hb = f2bf(v);
        hhi[i] = hb; hlo[i] = f2bf(v - bf2f(hb));    // buffer 0 = h_{-1}
    } else if (idx < 33024+65536+8192) {
        int i = idx - (33024+65536);
        float v = r0[i & 63];
        u16 hb = f2bf(v);
        xrhi[i] = hb; xrlo[i] = f2bf(v - bf2f(hb));
    } else if (idx < 33024+65536+8192+4096) {
        pflags[idx - (33024+65536+8192)] = 0u;
    } else if (idx < 33024+65536+8192+4096+64) {
        gsync[idx - (33024+65536+8192+4096)] = 0u;
    }
}

// ---------------- persistent kernel ----------------

__device__ __forceinline__ void gbar(u32* gs, u32 e){
    __threadfence();
    __syncthreads();
    if (threadIdx.x == 0) {
        u32* cnt  = gs;
        u32* flag = gs + 32;
        if (__hip_atomic_fetch_add(cnt, 1u, __ATOMIC_ACQ_REL, __HIP_MEMORY_SCOPE_AGENT) == 255u) {
            __hip_atomic_store(cnt, 0u, __ATOMIC_RELAXED, __HIP_MEMORY_SCOPE_AGENT);
            __hip_atomic_store(flag, e, __ATOMIC_RELEASE, __HIP_MEMORY_SCOPE_AGENT);
        } else {
            // relaxed spin (no per-poll L2 invalidate), single acquire at exit
            while (__hip_atomic_load(flag, __ATOMIC_RELAXED, __HIP_MEMORY_SCOPE_AGENT) < e)
                __builtin_amdgcn_s_sleep(1);
            (void)__hip_atomic_load(flag, __ATOMIC_ACQUIRE, __HIP_MEMORY_SCOPE_AGENT);
        }
    }
    __syncthreads();
}

__device__ __forceinline__ float blkMax(float v, float* red){
    #pragma unroll
    for (int o=32;o;o>>=1) v = fmaxf(v, __shfl_xor(v,o,64));
    if ((threadIdx.x & 63) == 0) red[threadIdx.x>>6] = v;
    __syncthreads();
    float r = red[0];
    #pragma unroll
    for (int i=1;i<8;i++) r = fmaxf(r, red[i]);
    return r;
}
__device__ __forceinline__ float blkSum(float v, float* red){
    #pragma unroll
    for (int o=32;o;o>>=1) v += __shfl_xor(v,o,64);
    if ((threadIdx.x & 63) == 0) red[threadIdx.x>>6] = v;
    __syncthreads();
    float r = red[0];
    #pragma unroll
    for (int i=1;i<8;i++) r += red[i];
    return r;
}

__launch_bounds__(512)
__global__ void mann_persist(const u16* __restrict__ embsb, const float* __restrict__ embsf,
                             const u16* __restrict__ WT,
                             const float* __restrict__ biasp, const u16* __restrict__ Wk,
                             const float* __restrict__ kbias,
                             u16* __restrict__ hhi, u16* __restrict__ hlo,
                             u16* __restrict__ xrhi, u16* __restrict__ xrlo,
                             const float* __restrict__ mem0, const float* __restrict__ c0,
                             float* __restrict__ out,
                             float* __restrict__ pairbuf, u32* __restrict__ pflags,
                             u32* __restrict__ gsync){
    // LDS: 133120 + 2048 + 2048 + 1024 + 2048 + 2048 + 2048 + 128 = 144512 B (<160K, 1 WG/CU)
    __shared__ float mem_lds[512*65];   // mem half, stride 65 (conflict-free scalar access)
    __shared__ float h_lds[512];
    __shared__ float emb_lds[512];
    __shared__ float keys_lds[256];     // [0:64) k_r, [64:128) k_w, [128:192) e, [192:256) a
    __shared__ float er_lds[512];
    __shared__ float ew_lds[512];
    __shared__ float urp[512];
    __shared__ float red[32];

    const int w    = blockIdx.x;
    const int tid  = threadIdx.x;
    // B role: pair (w, w^8) shares batch -> same XCD under round-robin dispatch
    const int batch = ((w>>4)<<3) + (w&7);
    const int half  = (w>>3)&1;
    const int mate  = w ^ 8;
    // A role (first 128 WGs): output tile [32 batches x 64 packed gate cols]
    const bool isA = (w < 128);
    const int bg = w & 3, cg = w >> 2;
    const int lane = tid & 63, wv = tid >> 6;
    const int rr = wv >> 2, cq = wv & 3;      // 2 row-waves x 4 col-waves
    const int mrow = lane & 15, q = lane >> 4;

    // persistent LSTM cell state in registers (A waves own (b, n) slices)
    float creg[4];
    const int nA = cg*16 + cq*4 + (mrow>>2);
    if (isA) { float cv = c0[nA]; creg[0]=creg[1]=creg[2]=creg[3]=cv; }

    // load my mem half into LDS (broadcast mem0 across batch)
    {
        const float* src = mem0 + (size_t)(half*512)*64;
        for (int i = tid; i < 512*64; i += 512)
            mem_lds[(i>>6)*65 + (i&63)] = src[i];
    }
    __syncthreads();

    for (int t = 0; t < T_STEPS; ++t) {
        // ---------------- PHASE A: gates GEMM + LSTM ----------------
        if (isA) {
            const int  arow = bg*32 + rr*16 + mrow;       // batch row for A frags
            const int  bcol = cg*64 + cq*16 + mrow;       // packed gate col
            floatx4 acc = {0.f,0.f,0.f,0.f};
            const u16* ap0 = embsb + ((size_t)((t<<7) + arow))*IDIM + q*8;
            const u16* bp0 = WT + (size_t)(q*G4 + bcol)*16;
            const size_t bstep = (size_t)4*G4*16;         // per-ks B stride (elems)
            #pragma unroll 4
            for (int ks = 0; ks < 16; ++ks) {             // k in [0,512): emb_t (2-term)
                short8 af = *(const short8*)(ap0 + ks*32);
                short8 bh = *(const short8*)(bp0 + (size_t)ks*bstep);
                short8 bl = *(const short8*)(bp0 + (size_t)ks*bstep + 8);
                acc = __builtin_amdgcn_mfma_f32_16x16x32_bf16(af, bh, acc, 0,0,0);
                acc = __builtin_amdgcn_mfma_f32_16x16x32_bf16(af, bl, acc, 0,0,0);
            }
            {
                const u16* arh = xrhi + arow*MW + q*8;    // k in [512,576): r_{t-1} (3-term)
                const u16* arl = xrlo + arow*MW + q*8;
                #pragma unroll
                for (int ks = 16; ks < 18; ++ks) {
                    short8 ah = *(const short8*)(arh + (ks-16)*32);
                    short8 al = *(const short8*)(arl + (ks-16)*32);
                    short8 bh = *(const short8*)(bp0 + (size_t)ks*bstep);
                    short8 bl = *(const short8*)(bp0 + (size_t)ks*bstep + 8);
                    acc = __builtin_amdgcn_mfma_f32_16x16x32_bf16(ah, bh, acc, 0,0,0);
                    acc = __builtin_amdgcn_mfma_f32_16x16x32_bf16(al, bh, acc, 0,0,0);
                    acc = __builtin_amdgcn_mfma_f32_16x16x32_bf16(ah, bl, acc, 0,0,0);
                }
            }
            {
                const u16* ahh = hhi + (t&1)*65536 + arow*CDIM + q*8;  // k in [576,1088): h_{t-1}
                const u16* ahl = hlo + (t&1)*65536 + arow*CDIM + q*8;
                #pragma unroll 4
                for (int ks = 18; ks < 34; ++ks) {
                    short8 ah = *(const short8*)(ahh + (ks-18)*32);
                    short8 al = *(const short8*)(ahl + (ks-18)*32);
                    short8 bh = *(const short8*)(bp0 + (size_t)ks*bstep);
                    short8 bl = *(const short8*)(bp0 + (size_t)ks*bstep + 8);
                    acc = __builtin_amdgcn_mfma_f32_16x16x32_bf16(ah, bh, acc, 0,0,0);
                    acc = __builtin_amdgcn_mfma_f32_16x16x32_bf16(al, bh, acc, 0,0,0);
                    acc = __builtin_amdgcn_mfma_f32_16x16x32_bf16(ah, bl, acc, 0,0,0);
                }
            }
            // epilogue: C layout col=lane&15 (packed j: n=j>>2, gate=j&3), row=q*4+rg
            const int jloc = lane & 15;
            const int gsl  = jloc & 3;
            const int ncol = cg*16 + cq*4 + (jloc>>2);
            const float bias = biasp[cg*64 + cq*16 + jloc];
            u16* hwh = hhi + ((t+1)&1)*65536;
            u16* hwl = hlo + ((t+1)&1)*65536;
            #pragma unroll
            for (int rg = 0; rg < 4; ++rg) {
                float gval = acc[rg] + bias;
                int base = lane & ~3;                     // 4 lanes = i,f,g,o of same n
                float iv = __shfl(gval, base+0, 64);
                float fv = __shfl(gval, base+1, 64);
                float gv = __shfl(gval, base+2, 64);
                float ov = __shfl(gval, base+3, 64);
                float cn = sigm(fv)*creg[rg] + sigm(iv)*tanhf(gv);
                creg[rg] = cn;
                float hn = sigm(ov)*tanhf(cn);
                if (gsl == 0) {
                    int b = bg*32 + rr*16 + q*4 + rg;
                    out[(size_t)(t*BSZ + b)*ODIM + ncol] = hn;
                    u16 hb = f2bf(hn);
                    hwh[b*CDIM + ncol] = hb;
                    hwl[b*CDIM + ncol] = f2bf(hn - bf2f(hb));
                }
            }
        }
        gbar(gsync, (u32)(2*t+1));

        // ---------------- PHASE B: keys + addressing + read + write ----------------
        {
            const u16* hch = hhi + ((t+1)&1)*65536 + batch*CDIM;   // h_t exact (hi+lo)
            const u16* hcl = hlo + ((t+1)&1)*65536 + batch*CDIM;
            h_lds[tid]   = bf2f(hch[tid]) + bf2f(hcl[tid]);
            emb_lds[tid] = embsf[((size_t)((t<<7) + batch))*IDIM + tid];  // fp32 emb
        }
        __syncthreads();

        if (tid < 256) {                                  // wave 3 (a-keys) uses emb: uniform
            const float* src = (tid < 192) ? h_lds : emb_lds;
            float a0=kbias[tid], a1=0.f, a2=0.f, a3=0.f;
            const uint2* wp = (const uint2*)Wk;
            #pragma unroll 8
            for (int d0 = 0; d0 < 512; d0 += 4) {
                uint2 wvv = wp[(d0>>2)*256 + tid];
                a0 += src[d0+0]*bf2f((u16)(wvv.x & 0xffffu));
                a1 += src[d0+1]*bf2f((u16)(wvv.x >> 16));
                a2 += src[d0+2]*bf2f((u16)(wvv.y & 0xffffu));
                a3 += src[d0+3]*bf2f((u16)(wvv.y >> 16));
            }
            float acc = (a0+a1)+(a2+a3);
            if (tid >= 192)      acc = tanhf(acc);        // a = tanh(emb@W_a+b_a)
            else if (tid >= 128) acc = sigm(acc);         // e = sigmoid(h@W_e+b_e)
            keys_lds[tid] = acc;
        }
        __syncthreads();

        // scores for both keys in one LDS pass (thread = slot)
        float s_r = 0.f, s_w = 0.f;
        {
            const float* mr = &mem_lds[tid*65];
            #pragma unroll 8
            for (int m = 0; m < 64; ++m) {
                float mv = mr[m];
                s_r += mv * keys_lds[m];
                s_w += mv * keys_lds[64+m];
            }
        }
        float Mr = blkMax(s_r, red+0);
        float Mw = blkMax(s_w, red+8);
        float erv = __expf(s_r - Mr), ewv = __expf(s_w - Mw);
        er_lds[tid] = erv; ew_lds[tid] = ewv;
        float Sr = blkSum(erv, red+16);
        float Sw = blkSum(ewv, red+24);

        // pair exchange 1: online-softmax merge stats (single exchange for max+sum)
        float* myp = pairbuf + w*128;
        const float* thp = pairbuf + mate*128;
        if (tid < 4) myp[64+tid] = (tid==0)?Mr:(tid==1)?Mw:(tid==2)?Sr:Sw;
        __threadfence();
        __syncthreads();
        if (tid == 0) {
            __hip_atomic_store(&pflags[w*16], (u32)(t+1), __ATOMIC_RELEASE, __HIP_MEMORY_SCOPE_AGENT);
            while (__hip_atomic_load(&pflags[mate*16], __ATOMIC_RELAXED, __HIP_MEMORY_SCOPE_AGENT) < (u32)(t+1))
                __builtin_amdgcn_s_sleep(1);
            (void)__hip_atomic_load(&pflags[mate*16], __ATOMIC_ACQUIRE, __HIP_MEMORY_SCOPE_AGENT);
        }
        __syncthreads();
        float Mr_p = thp[64], Mw_p = thp[65], Sr_p = thp[66], Sw_p = thp[67];
        float Mr_g = fmaxf(Mr, Mr_p), Mw_g = fmaxf(Mw, Mw_p);
        float scr = __expf(Mr - Mr_g);
        float scw = __expf(Mw - Mw_g);
        float Sr_tot = Sr*scr + Sr_p*__expf(Mr_p - Mr_g);
        float Sw_tot = Sw*scw + Sw_p*__expf(Mw_p - Mw_g);
        float wsc = scw / Sw_tot;                         // local exp -> normalized w_w

        // fused read-accum + erase/add update, col-major single LDS pass
        float urv = 0.f;
        {
            int m = tid & 63, grp = tid >> 6;
            float em = keys_lds[128+m], am = keys_lds[192+m];
            int n0 = grp*64;
            #pragma unroll 4
            for (int i = 0; i < 64; ++i) {
                int n = n0 + i;
                float mv = mem_lds[n*65 + m];
                urv += er_lds[n]*mv;                      // read uses pre-update mem
                float wn = ew_lds[n]*wsc;
                mem_lds[n*65+m] = mv*(1.f - wn*em) + wn*am;
            }
            urp[tid] = urv;
        }
        __syncthreads();
        float ur_tot = 0.f;
        if (tid < 64) {
            #pragma unroll
            for (int g2 = 0; g2 < 8; ++g2) ur_tot += urp[g2*64 + tid];
            myp[tid] = ur_tot * scr;                      // pre-scaled partial read
        }
        __threadfence();
        __syncthreads();
        if (half == 1) {                                  // one-directional: half1 -> half0
            if (tid == 0)
                __hip_atomic_store(&pflags[w*16+4], (u32)(t+1), __ATOMIC_RELEASE, __HIP_MEMORY_SCOPE_AGENT);
        } else {
            if (tid == 0) {
                while (__hip_atomic_load(&pflags[mate*16+4], __ATOMIC_RELAXED, __HIP_MEMORY_SCOPE_AGENT) < (u32)(t+1))
                    __builtin_amdgcn_s_sleep(1);
                (void)__hip_atomic_load(&pflags[mate*16+4], __ATOMIC_ACQUIRE, __HIP_MEMORY_SCOPE_AGENT);
            }
            __syncthreads();
            if (tid < 64) {
                float rv = (ur_tot*scr + thp[tid]) / Sr_tot;
                out[(size_t)(t*BSZ + batch)*ODIM + 512 + tid] = rv;
                u16 rb = f2bf(rv);
                xrhi[batch*MW + tid] = rb;
                xrlo[batch*MW + tid] = f2bf(rv - bf2f(rb));
            }
        }
        gbar(gsync, (u32)(2*t+2));
    }
}

// ---------------- launch ----------------

#define OFF_EMBSB  0u
#define OFF_WT     33554432u
#define OFF_BIASP  42467328u
#define OFF_WK     42475520u
#define OFF_KBIAS  42737664u
#define OFF_HHI    42738688u
#define OFF_HLO    43000832u
#define OFF_XRHI   43262976u
#define OFF_XRLO   43279360u
#define OFF_PAIR   43295744u
#define OFF_PFLAG  43426816u
#define OFF_GSYNC  43443200u
#define WS_NEED    43443456u

extern "C" void kernel_launch(void* const* d_in, const int* in_sizes, int n_in,
                              void* d_out, int out_size, void* d_ws, size_t ws_size,
                              hipStream_t stream) {
    if (ws_size < (size_t)WS_NEED) return;  // signal: need ~43.4 MB scratch

    const float* embs = (const float*)d_in[0];
    const float* w_ih = (const float*)d_in[1];
    const float* w_hh = (const float*)d_in[2];
    const float* b_ih = (const float*)d_in[3];
    const float* b_hh = (const float*)d_in[4];
    const float* h0   = (const float*)d_in[5];
    const float* c0   = (const float*)d_in[6];
    const float* r0   = (const float*)d_in[7];
    const float* mem0 = (const float*)d_in[8];
    const float* Wrk  = (const float*)d_in[9];
    const float* brk  = (const float*)d_in[10];
    const float* Wwk  = (const float*)d_in[11];
    const float* bwk  = (const float*)d_in[12];
    const float* We   = (const float*)d_in[13];
    const float* be   = (const float*)d_in[14];
    const float* Wa   = (const float*)d_in[15];
    const float* ba   = (const float*)d_in[16];

    char* ws = (char*)d_ws;
    u16*   embsb = (u16*)  (ws + OFF_EMBSB);
    u16*   WT    = (u16*)  (ws + OFF_WT);
    float* biasp = (float*)(ws + OFF_BIASP);
    u16*   Wk    = (u16*)  (ws + OFF_WK);
    float* kbias = (float*)(ws + OFF_KBIAS);
    u16*   hhi   = (u16*)  (ws + OFF_HHI);
    u16*   hlo   = (u16*)  (ws + OFF_HLO);
    u16*   xrhi  = (u16*)  (ws + OFF_XRHI);
    u16*   xrlo  = (u16*)  (ws + OFF_XRLO);
    float* pair  = (float*)(ws + OFF_PAIR);
    u32*   pflag = (u32*)  (ws + OFF_PFLAG);
    u32*   gsync = (u32*)  (ws + OFF_GSYNC);
    float* outp  = (float*)d_out;

    hipLaunchKernelGGL(prep_embs, dim3(16384), dim3(256), 0, stream, embs, embsb);
    hipLaunchKernelGGL(prep_wt,   dim3(1088),  dim3(256), 0, stream,
                       w_ih, w_hh, b_ih, b_hh, WT, biasp);
    hipLaunchKernelGGL(prep_misc, dim3(512),   dim3(256), 0, stream,
                       Wrk, Wwk, We, Wa, brk, bwk, be, ba, h0, r0,
                       Wk, kbias, hhi, hlo, xrhi, xrlo, pflag, gsync);

    const u16* embsb_c = embsb; const float* embsf_c = embs;
    const u16* WT_c = WT; const float* biasp_c = biasp;
    const u16* Wk_c = Wk; const float* kbias_c = kbias;
    const float* mem0_c = mem0; const float* c0_c = c0;
    void* kargs[] = { (void*)&embsb_c, (void*)&embsf_c, (void*)&WT_c, (void*)&biasp_c,
                      (void*)&Wk_c, (void*)&kbias_c, (void*)&hhi, (void*)&hlo,
                      (void*)&xrhi, (void*)&xrlo, (void*)&mem0_c,
                      (void*)&c0_c, (void*)&outp, (void*)&pair, (void*)&pflag,
                      (void*)&gsync };
    hipLaunchCooperativeKernel((void*)mann_persist, dim3(256), dim3(512), kargs, 0, stream);
}

// Round 3
// 16502.074 us; speedup vs baseline: 3.1165x; 3.1165x over previous
//
#include <hip/hip_runtime.h>

// MANN/NTM encoder, MI355X persistent-kernel, round 3.
// Key change vs r2: NO acquire/release/threadfence anywhere in the persistent loop
// (those lower to buffer_wbl2/buffer_inv = full L2 nuke per barrier -> 19 MB/step WT
// refetch, 48 ms). Cross-WG data goes through the coherent point via volatile
// (sc0 sc1) loads/stores; sync is a point-to-point flag DAG with relaxed
// system-scope atomics + s_waitcnt vmcnt(0). L2 stays warm -> weights resident.
// Phase A: 32 WGs x (16 batches x 512 packed gate cols), K=1088, split-bf16 MFMA
// (2-term emb, 3-term r/h). Phase B: all 256 WGs, per-batch-half NTM memory in LDS.

#define T_STEPS 256
#define BSZ     128
#define IDIM    512
#define CDIM    512
#define MW      64
#define G4      2048
#define ODIM    576

typedef unsigned short u16;
typedef unsigned int   u32;
typedef short  short8  __attribute__((ext_vector_type(8)));
typedef float  floatx4 __attribute__((ext_vector_type(4)));
typedef float  f4      __attribute__((ext_vector_type(4)));

__device__ __forceinline__ float bf2f(u16 h){ return __uint_as_float(((u32)h)<<16); }
__device__ __forceinline__ u16   f2bf(float f){ u32 u = __float_as_uint(f); return (u16)((u + 0x7fffu + ((u>>16)&1u))>>16); }
__device__ __forceinline__ float sigm(float x){ return 1.f/(1.f+__expf(-x)); }

// coherent-point (L2-bypass) data movement — no cache maintenance
__device__ __forceinline__ f4 vld4(const float* p){ return *(const volatile f4*)p; }
__device__ __forceinline__ float vldf(const float* p){ return *(const volatile float*)p; }
__device__ __forceinline__ void vstf(float* p, float v){ *(volatile float*)p = v; }

__device__ __forceinline__ void flag_set(u32* p, u32 v){
    __hip_atomic_store(p, v, __ATOMIC_RELAXED, __HIP_MEMORY_SCOPE_SYSTEM);
}
__device__ __forceinline__ void flag_wait(u32* p, u32 v){
    while (__hip_atomic_load(p, __ATOMIC_RELAXED, __HIP_MEMORY_SCOPE_SYSTEM) < v)
        __builtin_amdgcn_s_sleep(2);
}
#define VMDRAIN() asm volatile("s_waitcnt vmcnt(0)" ::: "memory")
#define CBAR()    asm volatile("" ::: "memory")

// ---------------- prep kernels ----------------

// Pack W = [w_ih | w_hh] -> bf16 hi/lo, gate-interleaved cols (j = 4n+g), k-major-8:
//   entry (kg,j) at WT[(kg*2048 + j)*16] = [hi0..hi7 | lo0..lo7], orig row ro=(j&3)*512+(j>>2)
__global__ void prep_wt(const float* __restrict__ wih, const float* __restrict__ whh,
                        const float* __restrict__ bih, const float* __restrict__ bhh,
                        u16* __restrict__ WT, float* __restrict__ biasp){
    int idx = blockIdx.x*256 + threadIdx.x;          // 136*2048 = 278528
    if (idx >= 136*G4) return;
    int j  = idx & (G4-1);
    int kg = idx >> 11;
    int ro = (j&3)*512 + (j>>2);
    u32 ohi[4], olo[4];
    #pragma unroll
    for (int p=0;p<4;p++){
        int k0 = kg*8 + p*2;
        float v0 = (k0   < 576) ? wih[ro*576 + k0  ] : whh[ro*512 + k0   - 576];
        float v1 = (k0+1 < 576) ? wih[ro*576 + k0+1] : whh[ro*512 + k0+1 - 576];
        u16 h0b = f2bf(v0), h1b = f2bf(v1);
        u16 l0b = f2bf(v0 - bf2f(h0b)), l1b = f2bf(v1 - bf2f(h1b));
        ohi[p] = (u32)h0b | ((u32)h1b<<16);
        olo[p] = (u32)l0b | ((u32)l1b<<16);
    }
    *(uint4*)&WT[(size_t)idx*16]     = make_uint4(ohi[0],ohi[1],ohi[2],ohi[3]);
    *(uint4*)&WT[(size_t)idx*16 + 8] = make_uint4(olo[0],olo[1],olo[2],olo[3]);
    if (idx < G4) biasp[j] = bih[ro] + bhh[ro];
}

// key weights bf16 interleaved; key biases; h/r fp32 state init; zero flags
__global__ void prep_misc(const float* __restrict__ Wrk, const float* __restrict__ Wwk,
                          const float* __restrict__ We,  const float* __restrict__ Wa,
                          const float* __restrict__ brk, const float* __restrict__ bwk,
                          const float* __restrict__ be,  const float* __restrict__ ba,
                          const float* __restrict__ h0,  const float* __restrict__ r0,
                          u16* __restrict__ Wk, float* __restrict__ kb,
                          float* __restrict__ hbuf, float* __restrict__ xr,
                          u32* __restrict__ hflag, u32* __restrict__ rflag,
                          u32* __restrict__ pflag){
    int idx = blockIdx.x*256 + threadIdx.x;          // grid 512*256 = 131072
    if (idx < 32768) {
        int d4 = idx >> 8, k = idx & 255;
        const float* src = (k<64)? Wrk + k*512 : (k<128)? Wwk + (k-64)*512
                         : (k<192)? We + (k-128)*512 : Wa + (k-192)*512;
        u32 a = (u32)f2bf(src[d4*4+0]) | ((u32)f2bf(src[d4*4+1])<<16);
        u32 b = (u32)f2bf(src[d4*4+2]) | ((u32)f2bf(src[d4*4+3])<<16);
        *(uint2*)&Wk[(size_t)idx*4] = make_uint2(a,b);
    } else if (idx < 33024) {
        int k = idx - 32768;
        kb[k] = (k<64)? brk[k] : (k<128)? bwk[k-64] : (k<192)? be[k-128] : ba[k-192];
    } else if (idx < 98560) {
        int i = idx - 33024;
        hbuf[65536 + i] = h0[i & 511];               // slot 1 = h_{-1}
    } else if (idx < 106752) {
        int i = idx - 98560;
        xr[i] = r0[i & 63];
    } else if (idx < 107776) {
        hflag[idx - 106752] = 0u;
    } else if (idx < 109824) {
        rflag[idx - 107776] = 0u;
    } else if (idx < 113920) {
        pflag[idx - 109824] = 0u;
    }
}

// ---------------- persistent kernel ----------------

__device__ __forceinline__ short8 pack_hi(f4 a, f4 b){
    union { short8 s; u16 u[8]; } r;
    r.u[0]=f2bf(a[0]); r.u[1]=f2bf(a[1]); r.u[2]=f2bf(a[2]); r.u[3]=f2bf(a[3]);
    r.u[4]=f2bf(b[0]); r.u[5]=f2bf(b[1]); r.u[6]=f2bf(b[2]); r.u[7]=f2bf(b[3]);
    return r.s;
}
__device__ __forceinline__ void pack_hilo(f4 a, f4 b, short8& hh, short8& ll){
    union { short8 s; u16 u[8]; } H, L;
    float v[8] = {a[0],a[1],a[2],a[3],b[0],b[1],b[2],b[3]};
    #pragma unroll
    for (int i=0;i<8;i++){ u16 hb = f2bf(v[i]); H.u[i]=hb; L.u[i]=f2bf(v[i]-bf2f(hb)); }
    hh = H.s; ll = L.s;
}

__device__ __forceinline__ float blkMax(float v, float* red){
    #pragma unroll
    for (int o=32;o;o>>=1) v = fmaxf(v, __shfl_xor(v,o,64));
    if ((threadIdx.x & 63) == 0) red[threadIdx.x>>6] = v;
    __syncthreads();
    float r = red[0];
    #pragma unroll
    for (int i=1;i<8;i++) r = fmaxf(r, red[i]);
    return r;
}
__device__ __forceinline__ float blkSum(float v, float* red){
    #pragma unroll
    for (int o=32;o;o>>=1) v += __shfl_xor(v,o,64);
    if ((threadIdx.x & 63) == 0) red[threadIdx.x>>6] = v;
    __syncthreads();
    float r = red[0];
    #pragma unroll
    for (int i=1;i<8;i++) r += red[i];
    return r;
}

#define BSTEP ((size_t)(4*G4*16))

__launch_bounds__(512)
__global__ void mann_persist(const float* __restrict__ embs, const u16* __restrict__ WT,
                             const float* __restrict__ biasp, const u16* __restrict__ Wk,
                             const float* __restrict__ kbias,
                             float* __restrict__ hbuf, float* __restrict__ xr,
                             const float* __restrict__ mem0, const float* __restrict__ c0,
                             float* __restrict__ out, float* __restrict__ pairbuf,
                             u32* __restrict__ hflag, u32* __restrict__ rflag,
                             u32* __restrict__ pflag){
    __shared__ float mem_lds[512*65];
    __shared__ float h_lds[512];
    __shared__ float emb_lds[512];
    __shared__ float keys_lds[256];     // [0:64) k_r, [64:128) k_w, [128:192) e, [192:256) a
    __shared__ float er_lds[512];       // also keys-GEMV partial scratch
    __shared__ float ew_lds[512];
    __shared__ float urp[512];
    __shared__ float red[32];
    __shared__ float xch[8];

    const int w    = blockIdx.x;
    const int tid  = threadIdx.x;
    const int batch = ((w>>4)<<3) + (w&7);     // B role batch
    const int half  = (w>>3)&1;
    const int mate  = w ^ 8;
    const bool isA = (w < 32);
    const int bgrp = w >> 2, cgrp = w & 3;     // A role: batches [bgrp*16,+16), cols [cgrp*512,+512)
    const int lane = tid & 63, wv = tid >> 6;
    const int jl = lane & 15, q = lane >> 4;
    const int colbase = cgrp*512 + wv*64;      // + tl*16 + jl

    // persistent LSTM cell state: lane owns (b=bgrp*16+q*4+rg, n=(colbase+tl*16+jl)>>2)
    float creg[16];
    if (isA) {
        #pragma unroll
        for (int tl=0; tl<4; ++tl) {
            float cv = c0[(colbase + tl*16 + jl) >> 2];
            creg[tl*4+0]=cv; creg[tl*4+1]=cv; creg[tl*4+2]=cv; creg[tl*4+3]=cv;
        }
    }

    // load my mem half into LDS (broadcast mem0 across batch)
    {
        const float* src = mem0 + (size_t)(half*512)*64;
        for (int i = tid; i < 512*64; i += 512)
            mem_lds[(i>>6)*65 + (i&63)] = src[i];
    }
    __syncthreads();

    for (int t = 0; t < T_STEPS; ++t) {
        // ---------------- PHASE A: gates GEMM + LSTM (WGs 0..31) ----------------
        if (isA) {
            u32 tgt = (u32)t;
            if (tid < 16)      flag_wait(&rflag[(bgrp*16 + tid)*16], tgt);
            else if (tid < 20) flag_wait(&hflag[(bgrp*4 + (tid-16))*32], tgt);
            __syncthreads();
            CBAR();

            const int bA = bgrp*16 + jl;                       // A-frag row -> batch
            const float* embrow = embs + ((size_t)(t*BSZ + bA))*IDIM;
            const float* hrow   = hbuf + ((t+1)&1)*65536 + bA*CDIM;   // h_{t-1}
            const float* rrow   = xr + bA*MW;
            const u16* bp0 = WT + ((size_t)q*G4 + colbase + jl)*16;

            floatx4 acc[4] = {{0.f,0.f,0.f,0.f},{0.f,0.f,0.f,0.f},
                              {0.f,0.f,0.f,0.f},{0.f,0.f,0.f,0.f}};
            #pragma unroll 2
            for (int ks = 0; ks < 16; ++ks) {                  // emb: 2-term
                f4 e0 = *(const f4*)(embrow + ks*32 + q*8);
                f4 e1 = *(const f4*)(embrow + ks*32 + q*8 + 4);
                short8 af = pack_hi(e0, e1);
                const u16* bks = bp0 + (size_t)ks*BSTEP;
                #pragma unroll
                for (int tl = 0; tl < 4; ++tl) {
                    short8 bh = *(const short8*)(bks + tl*256);
                    short8 bl = *(const short8*)(bks + tl*256 + 8);
                    acc[tl] = __builtin_amdgcn_mfma_f32_16x16x32_bf16(af, bh, acc[tl], 0,0,0);
                    acc[tl] = __builtin_amdgcn_mfma_f32_16x16x32_bf16(af, bl, acc[tl], 0,0,0);
                }
            }
            #pragma unroll
            for (int ks = 16; ks < 18; ++ks) {                 // r_{t-1}: 3-term
                f4 r0v = vld4(rrow + (ks-16)*32 + q*8);
                f4 r1v = vld4(rrow + (ks-16)*32 + q*8 + 4);
                short8 ah, al; pack_hilo(r0v, r1v, ah, al);
                const u16* bks = bp0 + (size_t)ks*BSTEP;
                #pragma unroll
                for (int tl = 0; tl < 4; ++tl) {
                    short8 bh = *(const short8*)(bks + tl*256);
                    short8 bl = *(const short8*)(bks + tl*256 + 8);
                    acc[tl] = __builtin_amdgcn_mfma_f32_16x16x32_bf16(ah, bh, acc[tl], 0,0,0);
                    acc[tl] = __builtin_amdgcn_mfma_f32_16x16x32_bf16(al, bh, acc[tl], 0,0,0);
                    acc[tl] = __builtin_amdgcn_mfma_f32_16x16x32_bf16(ah, bl, acc[tl], 0,0,0);
                }
            }
            #pragma unroll 2
            for (int ks = 18; ks < 34; ++ks) {                 // h_{t-1}: 3-term
                f4 h0v = vld4(hrow + (ks-18)*32 + q*8);
                f4 h1v = vld4(hrow + (ks-18)*32 + q*8 + 4);
                short8 ah, al; pack_hilo(h0v, h1v, ah, al);
                const u16* bks = bp0 + (size_t)ks*BSTEP;
                #pragma unroll
                for (int tl = 0; tl < 4; ++tl) {
                    short8 bh = *(const short8*)(bks + tl*256);
                    short8 bl = *(const short8*)(bks + tl*256 + 8);
                    acc[tl] = __builtin_amdgcn_mfma_f32_16x16x32_bf16(ah, bh, acc[tl], 0,0,0);
                    acc[tl] = __builtin_amdgcn_mfma_f32_16x16x32_bf16(al, bh, acc[tl], 0,0,0);
                    acc[tl] = __builtin_amdgcn_mfma_f32_16x16x32_bf16(ah, bl, acc[tl], 0,0,0);
                }
            }
            // epilogue: C row=q*4+rg (batch), col=jl (packed j); 4 lanes = i,f,g,o of one n
            float* hw = hbuf + (t&1)*65536;
            #pragma unroll
            for (int tl = 0; tl < 4; ++tl) {
                int j = colbase + tl*16 + jl;
                int g = j & 3, n = j >> 2;
                float bias = biasp[j];
                #pragma unroll
                for (int rg = 0; rg < 4; ++rg) {
                    float gval = acc[tl][rg] + bias;
                    int base = lane & ~3;
                    float iv = __shfl(gval, base+0, 64);
                    float fv = __shfl(gval, base+1, 64);
                    float gv = __shfl(gval, base+2, 64);
                    float ov = __shfl(gval, base+3, 64);
                    float cn = sigm(fv)*creg[tl*4+rg] + sigm(iv)*tanhf(gv);
                    creg[tl*4+rg] = cn;
                    float hn = sigm(ov)*tanhf(cn);
                    if (g == 0) {
                        int b = bgrp*16 + q*4 + rg;
                        out[(size_t)(t*BSZ + b)*ODIM + n] = hn;
                        vstf(hw + b*CDIM + n, hn);
                    }
                }
            }
            VMDRAIN();
            __syncthreads();
            if (tid == 0) flag_set(&hflag[w*32], (u32)(t+1));
        }

        // ---------------- PHASE B: keys + addressing + read + write (all WGs) -------
        if (tid < 4) flag_wait(&hflag[((batch>>4)*4 + tid)*32], (u32)(t+1));
        __syncthreads();
        CBAR();
        h_lds[tid]   = vldf(hbuf + (t&1)*65536 + batch*CDIM + tid);
        emb_lds[tid] = embs[((size_t)(t*BSZ + batch))*IDIM + tid];
        __syncthreads();

        // keys GEMV split over 512 threads (256 keys x 2 k-halves), Wk L2-resident
        {
            int key = tid & 255, kh = tid >> 8;
            const float* src = (key < 192) ? h_lds : emb_lds;
            const uint2* wp = (const uint2*)Wk;
            float a0=0.f, a1=0.f, a2=0.f, a3=0.f;
            int d0 = kh*256;
            #pragma unroll 8
            for (int dd = 0; dd < 256; dd += 4) {
                uint2 wvv = wp[((d0+dd)>>2)*256 + key];
                a0 += src[d0+dd+0]*bf2f((u16)(wvv.x & 0xffffu));
                a1 += src[d0+dd+1]*bf2f((u16)(wvv.x >> 16));
                a2 += src[d0+dd+2]*bf2f((u16)(wvv.y & 0xffffu));
                a3 += src[d0+dd+3]*bf2f((u16)(wvv.y >> 16));
            }
            er_lds[tid] = (a0+a1)+(a2+a3);
        }
        __syncthreads();
        if (tid < 256) {
            float acc = kbias[tid] + er_lds[tid] + er_lds[tid+256];
            if (tid >= 192)      acc = tanhf(acc);
            else if (tid >= 128) acc = sigm(acc);
            keys_lds[tid] = acc;
        }
        __syncthreads();

        // scores for both keys, one LDS pass (thread = slot)
        float s_r = 0.f, s_w = 0.f;
        {
            const float* mr = &mem_lds[tid*65];
            #pragma unroll 8
            for (int m = 0; m < 64; ++m) {
                float mv = mr[m];
                s_r += mv * keys_lds[m];
                s_w += mv * keys_lds[64+m];
            }
        }
        float Mr = blkMax(s_r, red+0);
        float Mw = blkMax(s_w, red+8);
        float erv = __expf(s_r - Mr), ewv = __expf(s_w - Mw);
        er_lds[tid] = erv; ew_lds[tid] = ewv;
        float Sr = blkSum(erv, red+16);
        float Sw = blkSum(ewv, red+24);

        // pair exchange: online-softmax merge stats
        float* myp = pairbuf + w*128;
        const float* thp = pairbuf + mate*128;
        if (tid == 0) {
            vstf(myp+64, Mr); vstf(myp+65, Mw); vstf(myp+66, Sr); vstf(myp+67, Sw);
            VMDRAIN();
            flag_set(&pflag[w*16], (u32)(t+1));
            flag_wait(&pflag[mate*16], (u32)(t+1));
        }
        __syncthreads();
        CBAR();
        if (tid < 4) xch[tid] = vldf(thp + 64 + tid);
        __syncthreads();
        float Mr_p = xch[0], Mw_p = xch[1], Sr_p = xch[2], Sw_p = xch[3];
        float Mr_g = fmaxf(Mr, Mr_p), Mw_g = fmaxf(Mw, Mw_p);
        float scr = __expf(Mr - Mr_g);
        float scw = __expf(Mw - Mw_g);
        float Sr_tot = Sr*scr + Sr_p*__expf(Mr_p - Mr_g);
        float Sw_tot = Sw*scw + Sw_p*__expf(Mw_p - Mw_g);
        float wsc = scw / Sw_tot;

        // fused read-accum + erase/add update, col-major single LDS pass
        {
            int m = tid & 63, grp = tid >> 6;
            float em = keys_lds[128+m], am = keys_lds[192+m];
            float urv = 0.f;
            int n0 = grp*64;
            #pragma unroll 4
            for (int i = 0; i < 64; ++i) {
                int n = n0 + i;
                float mv = mem_lds[n*65 + m];
                urv += er_lds[n]*mv;
                float wn = ew_lds[n]*wsc;
                mem_lds[n*65+m] = mv*(1.f - wn*em) + wn*am;
            }
            urp[tid] = urv;
        }
        __syncthreads();
        float ur_tot = 0.f;
        if (tid < 64) {
            #pragma unroll
            for (int g2 = 0; g2 < 8; ++g2) ur_tot += urp[g2*64 + tid];
        }
        if (half == 1) {                                  // half1 -> half0 partials
            if (tid < 64) vstf(myp + tid, ur_tot * scr);
            VMDRAIN();
            if (tid == 0) flag_set(&pflag[w*16+4], (u32)(t+1));
        } else {
            if (tid == 0) flag_wait(&pflag[mate*16+4], (u32)(t+1));
            CBAR();
            if (tid < 64) {
                float rv = (ur_tot*scr + vldf(thp + tid)) / Sr_tot;
                out[(size_t)(t*BSZ + batch)*ODIM + 512 + tid] = rv;
                vstf(xr + batch*MW + tid, rv);
            }
            VMDRAIN();
            if (tid == 0) flag_set(&rflag[batch*16], (u32)(t+1));
        }
    }
}

// ---------------- launch ----------------

#define OFF_WT     0u
#define OFF_BIASP  8912896u
#define OFF_WK     8921088u
#define OFF_KBIAS  9183232u
#define OFF_HBUF   9184256u
#define OFF_XR     9708544u
#define OFF_PAIR   9741312u
#define OFF_HFLAG  9872384u
#define OFF_RFLAG  9876480u
#define OFF_PFLAG  9884672u
#define WS_NEED    9901056u

extern "C" void kernel_launch(void* const* d_in, const int* in_sizes, int n_in,
                              void* d_out, int out_size, void* d_ws, size_t ws_size,
                              hipStream_t stream) {
    if (ws_size < (size_t)WS_NEED) return;

    const float* embs = (const float*)d_in[0];
    const float* w_ih = (const float*)d_in[1];
    const float* w_hh = (const float*)d_in[2];
    const float* b_ih = (const float*)d_in[3];
    const float* b_hh = (const float*)d_in[4];
    const float* h0   = (const float*)d_in[5];
    const float* c0   = (const float*)d_in[6];
    const float* r0   = (const float*)d_in[7];
    const float* mem0 = (const float*)d_in[8];
    const float* Wrk  = (const float*)d_in[9];
    const float* brk  = (const float*)d_in[10];
    const float* Wwk  = (const float*)d_in[11];
    const float* bwk  = (const float*)d_in[12];
    const float* We   = (const float*)d_in[13];
    const float* be   = (const float*)d_in[14];
    const float* Wa   = (const float*)d_in[15];
    const float* ba   = (const float*)d_in[16];

    char* ws = (char*)d_ws;
    u16*   WT    = (u16*)  (ws + OFF_WT);
    float* biasp = (float*)(ws + OFF_BIASP);
    u16*   Wk    = (u16*)  (ws + OFF_WK);
    float* kbias = (float*)(ws + OFF_KBIAS);
    float* hbuf  = (float*)(ws + OFF_HBUF);
    float* xrp   = (float*)(ws + OFF_XR);
    float* pair  = (float*)(ws + OFF_PAIR);
    u32*   hflag = (u32*)  (ws + OFF_HFLAG);
    u32*   rflag = (u32*)  (ws + OFF_RFLAG);
    u32*   pflag = (u32*)  (ws + OFF_PFLAG);
    float* outp  = (float*)d_out;

    hipLaunchKernelGGL(prep_wt,   dim3(1088), dim3(256), 0, stream,
                       w_ih, w_hh, b_ih, b_hh, WT, biasp);
    hipLaunchKernelGGL(prep_misc, dim3(512),  dim3(256), 0, stream,
                       Wrk, Wwk, We, Wa, brk, bwk, be, ba, h0, r0,
                       Wk, kbias, hbuf, xrp, hflag, rflag, pflag);

    const float* embs_c = embs; const u16* WT_c = WT; const float* biasp_c = biasp;
    const u16* Wk_c = Wk; const float* kbias_c = kbias;
    const float* mem0_c = mem0; const float* c0_c = c0;
    void* kargs[] = { (void*)&embs_c, (void*)&WT_c, (void*)&biasp_c, (void*)&Wk_c,
                      (void*)&kbias_c, (void*)&hbuf, (void*)&xrp, (void*)&mem0_c,
                      (void*)&c0_c, (void*)&outp, (void*)&pair,
                      (void*)&hflag, (void*)&rflag, (void*)&pflag };
    hipLaunchCooperativeKernel((void*)mann_persist, dim3(256), dim3(512), kargs, 0, stream);
}